// Round 12
// baseline (464.453 us; speedup 1.0000x reference)
//
#include <hip/hip_runtime.h>
#include <hip/hip_bf16.h>

#define IN_DIM 300
#define XDIM   320      // x row padded: 300 vals + bias-one at col 300 + zeros
#define MEM    1024
#define NTREE  16383

typedef _Float16 half8 __attribute__((ext_vector_type(8)));
typedef float    f32x4 __attribute__((ext_vector_type(4)));

__device__ __forceinline__ float sigf(float x) { return 1.0f / (1.0f + __expf(-x)); }
__device__ __forceinline__ float tanhfast(float x) { return 2.0f / (1.0f + __expf(-2.0f * x)) - 1.0f; }

#define GLOAD_LDS16(g, l) \
    __builtin_amdgcn_global_load_lds((const __attribute__((address_space(1))) void*)(g), \
                                     (__attribute__((address_space(3))) void*)(l), 16, 0, 0)

// ---------------------------------------------------------------------------
// Pack (one-time): Wiou16 = [Wih;Woh;Wuh] (3072x1024 fp16), Wfh16 (1024x1024),
// x16 (16384x320: [x | 1.0 | 0...]), Bx (4096x320: [Wgx | bgx+bgh | 0...],
// rows g=i,o,u,f).
// ---------------------------------------------------------------------------
__global__ void pack_kernel(
    const float* __restrict__ embs,
    const float* __restrict__ Wix, const float* __restrict__ bix,
    const float* __restrict__ Wih, const float* __restrict__ bih,
    const float* __restrict__ Wfx, const float* __restrict__ bfx,
    const float* __restrict__ Wfh, const float* __restrict__ bfh,
    const float* __restrict__ Wox, const float* __restrict__ box_,
    const float* __restrict__ Woh, const float* __restrict__ boh,
    const float* __restrict__ Wux, const float* __restrict__ bux,
    const float* __restrict__ Wuh, const float* __restrict__ buh,
    _Float16* __restrict__ Wiou16, _Float16* __restrict__ Wfh16,
    _Float16* __restrict__ x16, _Float16* __restrict__ Bx)
{
    long long idx = (long long)blockIdx.x * blockDim.x + threadIdx.x;
    const long long n_wiou = 3072LL * 1024;
    const long long n_wfh  = 1024LL * 1024;
    const long long n_x    = 16384LL * XDIM;
    const long long n_bx   = 4096LL * XDIM;
    if (idx < n_wiou) {
        int m = (int)(idx >> 10), k = (int)(idx & 1023);
        int g = m >> 10, mm = m & 1023;
        const float* W = (g == 0) ? Wih : (g == 1) ? Woh : Wuh;
        Wiou16[idx] = (_Float16)W[(long long)mm * MEM + k];
        return;
    }
    idx -= n_wiou;
    if (idx < n_wfh) {
        Wfh16[idx] = (_Float16)Wfh[idx];
        return;
    }
    idx -= n_wfh;
    if (idx < n_x) {
        int node = (int)(idx / XDIM), j = (int)(idx % XDIM);
        float v = 0.f;
        if (node < NTREE) {
            if (j < IN_DIM) v = embs[(long long)node * IN_DIM + j];
            else if (j == IN_DIM) v = 1.0f;
        }
        x16[idx] = (_Float16)v;
        return;
    }
    idx -= n_x;
    if (idx < n_bx) {
        int r = (int)(idx / XDIM), j = (int)(idx % XDIM);
        int g = r >> 10, mm = r & 1023;
        const float* Wx = (g == 0) ? Wix : (g == 1) ? Wox : (g == 2) ? Wux : Wfx;
        const float* b1 = (g == 0) ? bix : (g == 1) ? box_ : (g == 2) ? bux : bfx;
        const float* b2 = (g == 0) ? bih : (g == 1) ? boh : (g == 2) ? buh : bfh;
        float v = 0.f;
        if (j < IN_DIM) v = Wx[(long long)mm * IN_DIM + j];
        else if (j == IN_DIM) v = b1[mm] + b2[mm];
        Bx[idx] = (_Float16)v;
    }
}

// ---------------------------------------------------------------------------
// GEMM tile core: C(BMxBN) = A(BMxK) * B(BNxK)^T. fp16 in / f32 MFMA / fp16
// out. 4 waves (2x2). Single-buffered LDS, m97 2-barrier structure (proven
// fastest at 2-phase: r2 63.7us vs r3-dbuf 79.6 / r5-BK64 69.3). XOR swizzle
// slot arithmetic (rule-21-compliant). BODY UNCHANGED since r6 — the hot
// <128,128,32> instantiation's codegen (VGPR 84) is the canary.
// ---------------------------------------------------------------------------
template<int BM, int BN, int BK>
__device__ __forceinline__ void gemm_tile(
    const _Float16* __restrict__ A, int lda,
    const _Float16* __restrict__ B, int ldb,
    _Float16* __restrict__ C, int ldc, int K,
    _Float16* ldsA, _Float16* ldsB)
{
    constexpr int FM = BM / 32, FN = BN / 32;
    constexpr int CPR = BK / 8, SWM = CPR - 1;
    constexpr int ACH = BM * BK / 2048, BCH = BN * BK / 2048;

    int tid = threadIdx.x, wave = tid >> 6, lane = tid & 63;
    int wr = (wave >> 1) * (BM / 2), wc = (wave & 1) * (BN / 2);
    int kq = (lane >> 4) * 8, rs = lane & 15;
    f32x4 acc[FM][FN] = {};

    for (int k0 = 0; k0 < K; k0 += BK) {
#pragma unroll
        for (int j = 0; j < ACH; ++j) {
            int c = j * 256 + tid;
            int row = c / CPR;
            int s = (c ^ row) & SWM;
            GLOAD_LDS16(A + (long long)row * lda + k0 + s * 8,
                        &ldsA[(j * 256 + wave * 64) * 8]);
        }
#pragma unroll
        for (int j = 0; j < BCH; ++j) {
            int c = j * 256 + tid;
            int row = c / CPR;
            int s = (c ^ row) & SWM;
            GLOAD_LDS16(B + (long long)row * ldb + k0 + s * 8,
                        &ldsB[(j * 256 + wave * 64) * 8]);
        }
        __syncthreads();
#pragma unroll
        for (int kk = 0; kk < BK; kk += 32) {
            half8 a[FM], b[FN];
#pragma unroll
            for (int i = 0; i < FM; ++i) {
                int r = wr + i * 16 + rs;
                int s = ((kk + kq) >> 3) ^ (r & SWM);
                a[i] = *(const half8*)&ldsA[r * BK + s * 8];
            }
#pragma unroll
            for (int i = 0; i < FN; ++i) {
                int r = wc + i * 16 + rs;
                int s = ((kk + kq) >> 3) ^ (r & SWM);
                b[i] = *(const half8*)&ldsB[r * BK + s * 8];
            }
#pragma unroll
            for (int mi = 0; mi < FM; ++mi)
#pragma unroll
                for (int ni = 0; ni < FN; ++ni)
                    acc[mi][ni] = __builtin_amdgcn_mfma_f32_16x16x32_f16(a[mi], b[ni], acc[mi][ni], 0, 0, 0);
        }
        __syncthreads();
    }
    // C/D layout: col = lane&15, row = (lane>>4)*4 + reg  [m89-verified]
    int crb = wr + (lane >> 4) * 4, ccb = wc + rs;
#pragma unroll
    for (int mi = 0; mi < FM; ++mi)
#pragma unroll
        for (int i = 0; i < 4; ++i) {
            long long r = crb + mi * 16 + i;
#pragma unroll
            for (int ni = 0; ni < FN; ++ni)
                C[r * ldc + ccb + ni * 16] = (_Float16)acc[mi][ni][i];
        }
}

template<int BM, int BN, int BK>
__global__ __launch_bounds__(256) void gemm_f16(
    const _Float16* __restrict__ A, int lda,
    const _Float16* __restrict__ B, int ldb,
    _Float16* __restrict__ C, int ldc, int K)
{
    __shared__ __align__(16) _Float16 ldsA[BM * BK];
    __shared__ __align__(16) _Float16 ldsB[BN * BK];
    gemm_tile<BM, BN, BK>(A + (long long)blockIdx.x * BM * lda, lda,
                          B + (long long)blockIdx.y * BN * ldb, ldb,
                          C + (long long)blockIdx.x * BM * ldc + (long long)blockIdx.y * BN,
                          ldc, K, ldsA, ldsB);
}

// Fused per-level GEMM: part1 = hsum @ Wiou^T (n x 3072), part2 = H @ Wfh^T
// (2n x 1024). Both K=1024. BK=32 for big levels (16KB LDS, occupancy-best);
// BK=128 for mid levels (serial K-step COUNT dominates at tiny grids).
template<int BM1, int BM2, int BK>
__global__ __launch_bounds__(256) void gemm_level(
    const _Float16* __restrict__ Hsum, const _Float16* __restrict__ Hc,
    const _Float16* __restrict__ Wiou, const _Float16* __restrict__ Wf,
    _Float16* __restrict__ houpre, _Float16* __restrict__ fpre,
    int G1, int G2)
{
    constexpr int BMX = (BM1 > BM2) ? BM1 : BM2;
    __shared__ __align__(16) _Float16 ldsA[BMX * BK];
    __shared__ __align__(16) _Float16 ldsB[128 * BK];
    int bx = blockIdx.x;
    if (bx < G1 * 24) {
        int nb = bx / G1, mb = bx % G1;
        gemm_tile<BM1, 128, BK>(Hsum + (long long)mb * BM1 * 1024, 1024,
                                Wiou + (long long)nb * 128 * 1024, 1024,
                                houpre + (long long)mb * BM1 * 3072 + nb * 128, 3072,
                                1024, ldsA, ldsB);
    } else {
        int b2 = bx - G1 * 24;
        int nb = b2 / G2, mb = b2 % G2;
        gemm_tile<BM2, 128, BK>(Hc + (long long)mb * BM2 * 1024, 1024,
                                Wf + (long long)nb * 128 * 1024, 1024,
                                fpre + (long long)mb * BM2 * 1024 + nb * 128, 1024,
                                1024, ldsA, ldsB);
    }
}

// ---------------------------------------------------------------------------
// Split-K tail GEMM (levels n <= 64): S=4 K-slices of 256, ONE K-step per
// block (BK=256). 128 blocks spread the 8.4 MB weight read over 4x the CUs
// and cut the serial K-chain 4 -> 1. fp16 partials (gemm_tile reused
// unchanged); slice s of iou -> houp + s*64*3072, f -> fp + s*128*1024.
// Stale A rows (> n / > 2n) produce garbage partial rows that the combine
// never reads (finite garbage only — MFMA C rows depend only on own A row).
// ---------------------------------------------------------------------------
__global__ __launch_bounds__(256) void tail_sk(
    const _Float16* __restrict__ Hsum, const _Float16* __restrict__ Hc,
    const _Float16* __restrict__ Wiou, const _Float16* __restrict__ Wf,
    _Float16* __restrict__ houp, _Float16* __restrict__ fp)
{
    __shared__ __align__(16) _Float16 ldsA[128 * 256];   // 64 KB
    __shared__ __align__(16) _Float16 ldsB[128 * 256];   // 64 KB
    int bx = blockIdx.x;
    int s = bx >> 5, r = bx & 31;
    int k0 = s * 256;
    if (r < 24) {   // iou: 64 rows x 128 cols, K-slice 256
        gemm_tile<64, 128, 256>(Hsum + k0, 1024,
                                Wiou + (long long)r * 128 * 1024 + k0, 1024,
                                houp + (long long)s * 64 * 3072 + r * 128, 3072,
                                256, ldsA, ldsB);
    } else {        // f: 128 rows x 128 cols, K-slice 256
        int nb = r - 24;
        gemm_tile<128, 128, 256>(Hc + k0, 1024,
                                 Wf + (long long)nb * 128 * 1024 + k0, 1024,
                                 fp + (long long)s * 128 * 1024 + nb * 128, 1024,
                                 256, ldsA, ldsB);
    }
}

// ---------------------------------------------------------------------------
// Split-K tail combine: sum 4 fp16 partials + Xp, activate, combine.
// cprev fp16. At lvl0 writes d_out = [c;h] f32.
// ---------------------------------------------------------------------------
__global__ void combine_tail_sk(
    const _Float16* __restrict__ houp,   // 4 x 64 x 3072
    const _Float16* __restrict__ fp,     // 4 x 128 x 1024
    const _Float16* __restrict__ cprev,
    const _Float16* __restrict__ Xp,
    _Float16* __restrict__ cout, _Float16* __restrict__ hout, _Float16* __restrict__ hsum,
    int n, int gx0, float* __restrict__ fin)
{
    int idx = blockIdx.x * blockDim.x + threadIdx.x;
    int npairs = (n > 1) ? (n >> 1) : 1;
    if (idx >= npairs * 128) return;
    int r = idx >> 7, m8 = (idx & 127) * 8;
    float hs[8];
#pragma unroll
    for (int j = 0; j < 8; ++j) hs[j] = 0.f;
    int pmax = (n > 1) ? 2 : 1;
    for (int t = 0; t < pmax; ++t) {
        int p = 2 * r + t;
        long long node = gx0 + p;
        float gi[8], go[8], gu[8], q0[8], q1[8];
        half8 pxi = *(const half8*)&Xp[node * 4096 + m8];
        half8 pxo = *(const half8*)&Xp[node * 4096 + 1024 + m8];
        half8 pxu = *(const half8*)&Xp[node * 4096 + 2048 + m8];
        half8 pxf = *(const half8*)&Xp[node * 4096 + 3072 + m8];
#pragma unroll
        for (int j = 0; j < 8; ++j) {
            gi[j] = (float)pxi[j]; go[j] = (float)pxo[j]; gu[j] = (float)pxu[j];
            q0[j] = (float)pxf[j]; q1[j] = (float)pxf[j];
        }
#pragma unroll
        for (int s = 0; s < 4; ++s) {
            const _Float16* hb = houp + ((long long)s * 64 + p) * 3072;
            half8 a = *(const half8*)&hb[m8];
            half8 b = *(const half8*)&hb[1024 + m8];
            half8 c = *(const half8*)&hb[2048 + m8];
            const _Float16* f0b = fp + ((long long)s * 128 + 2 * p) * 1024;
            const _Float16* f1b = fp + ((long long)s * 128 + 2 * p + 1) * 1024;
            half8 d = *(const half8*)&f0b[m8];
            half8 e = *(const half8*)&f1b[m8];
#pragma unroll
            for (int j = 0; j < 8; ++j) {
                gi[j] += (float)a[j]; go[j] += (float)b[j]; gu[j] += (float)c[j];
                q0[j] += (float)d[j]; q1[j] += (float)e[j];
            }
        }
        half8 pc0 = *(const half8*)&cprev[(long long)(2 * p) * 1024 + m8];
        half8 pc1 = *(const half8*)&cprev[(long long)(2 * p + 1) * 1024 + m8];
        float cw[8], hw[8];
#pragma unroll
        for (int j = 0; j < 8; ++j) {
            float i  = sigf(gi[j]);
            float o  = sigf(go[j]);
            float u  = tanhfast(gu[j]);
            float f0 = sigf(q0[j]);
            float f1 = sigf(q1[j]);
            float c = i * u + f0 * (float)pc0[j] + f1 * (float)pc1[j];
            float h = o * tanhfast(c);
            cw[j] = c; hw[j] = h; hs[j] += h;
        }
        if (fin) {                      // lvl0: write [c;h] f32 to d_out
            f32x4 v0 = {cw[0], cw[1], cw[2], cw[3]}, v1 = {cw[4], cw[5], cw[6], cw[7]};
            f32x4 w0 = {hw[0], hw[1], hw[2], hw[3]}, w1 = {hw[4], hw[5], hw[6], hw[7]};
            *(f32x4*)&fin[m8] = v0;            *(f32x4*)&fin[m8 + 4] = v1;
            *(f32x4*)&fin[1024 + m8] = w0;     *(f32x4*)&fin[1024 + m8 + 4] = w1;
        } else {
            half8 cv, hv;
#pragma unroll
            for (int j = 0; j < 8; ++j) { cv[j] = (_Float16)cw[j]; hv[j] = (_Float16)hw[j]; }
            *(half8*)&cout[(long long)p * 1024 + m8] = cv;
            *(half8*)&hout[(long long)p * 1024 + m8] = hv;
        }
    }
    if (!fin) {
        half8 sv;
#pragma unroll
        for (int j = 0; j < 8; ++j) sv[j] = (_Float16)hs[j];
        *(half8*)&hsum[(long long)r * 1024 + m8] = sv;
    }
}

// ---------------------------------------------------------------------------
// Leaf fused GEMM+combine: tile 64 leaves x 128 cols, 3 gate accumulators
// (i,o,u), K=320, single-buffered (28 KB LDS). Writes cleaf/h/hsum.
// ---------------------------------------------------------------------------
__global__ __launch_bounds__(256) void leaf_fused(
    const _Float16* __restrict__ x16, const _Float16* __restrict__ Bx,
    _Float16* __restrict__ cleaf, _Float16* __restrict__ hleaf,
    _Float16* __restrict__ hsum)
{
    constexpr int BK = 32, CPR = 4, SWM = 3;
    __shared__ __align__(16) _Float16 lA[64 * BK];
    __shared__ __align__(16) _Float16 lB[384 * BK];
    int tid = threadIdx.x, wave = tid >> 6, lane = tid & 63;
    int kq = (lane >> 4) * 8, rs = lane & 15;
    int wr = (wave >> 1) * 32, wc = (wave & 1) * 64;
    int m0 = blockIdx.x * 64, c0 = blockIdx.y * 128;
    const _Float16* A = x16 + (size_t)(8191 + m0) * XDIM;

    f32x4 acc[3][2][4] = {};
    for (int t = 0; t < 10; ++t) {     // K = 320
        int k0 = t * BK;
        {   // A: 256 chunks, 1/thread
            int c = tid, row = c / CPR, s = (c ^ row) & SWM;
            GLOAD_LDS16(A + (long long)row * XDIM + k0 + s * 8, &lA[(wave * 64) * 8]);
        }
#pragma unroll
        for (int j = 0; j < 6; ++j) {   // B: 1536 chunks (3 gate tiles x 128)
            int c = j * 256 + tid;
            int row = c / CPR, s = (c ^ row) & SWM;
            int g = row >> 7, rr = row & 127;
            GLOAD_LDS16(Bx + (long long)(g * 1024 + c0 + rr) * XDIM + k0 + s * 8,
                        &lB[(j * 256 + wave * 64) * 8]);
        }
        __syncthreads();
        half8 a[2], b[3][4];
#pragma unroll
        for (int mi = 0; mi < 2; ++mi) {
            int r = wr + mi * 16 + rs;
            int s = (kq >> 3) ^ (r & SWM);
            a[mi] = *(const half8*)&lA[r * BK + s * 8];
        }
#pragma unroll
        for (int g = 0; g < 3; ++g)
#pragma unroll
            for (int nj = 0; nj < 4; ++nj) {
                int r = g * 128 + wc + nj * 16 + rs;
                int s = (kq >> 3) ^ (r & SWM);
                b[g][nj] = *(const half8*)&lB[r * BK + s * 8];
            }
#pragma unroll
        for (int g = 0; g < 3; ++g)
#pragma unroll
            for (int mi = 0; mi < 2; ++mi)
#pragma unroll
                for (int nj = 0; nj < 4; ++nj)
                    acc[g][mi][nj] = __builtin_amdgcn_mfma_f32_16x16x32_f16(a[mi], b[g][nj], acc[g][mi][nj], 0, 0, 0);
        __syncthreads();
    }
    int lrb = wr + (lane >> 4) * 4;
#pragma unroll
    for (int mi = 0; mi < 2; ++mi)
#pragma unroll
        for (int nj = 0; nj < 4; ++nj) {
            int col = c0 + wc + nj * 16 + rs;
            float hpair = 0.f;
#pragma unroll
            for (int i = 0; i < 4; ++i) {
                long long l = m0 + lrb + mi * 16 + i;
                float cc = sigf(acc[0][mi][nj][i]) * tanhfast(acc[2][mi][nj][i]);
                float hh = sigf(acc[1][mi][nj][i]) * tanhfast(cc);
                cleaf[l * 1024 + col] = (_Float16)cc;
                hleaf[l * 1024 + col] = (_Float16)hh;
                if (i & 1) hsum[(l >> 1) * 1024 + col] = (_Float16)(hpair + hh);
                else hpair = hh;
            }
        }
}

// ---------------------------------------------------------------------------
// Combine: gates from houpre + Xp(iou cols 0..3071), f per child from fpre +
// Xp(col 3072+), c = i*u + f0*c0 + f1*c1, h = o*tanh(c). c stored fp16.
// Emits c/h/hsum; at lvl0 writes d_out = [c;h] f32 from registers instead.
// ---------------------------------------------------------------------------
__global__ void combine_level(
    const _Float16* __restrict__ houpre, const _Float16* __restrict__ fpre,
    const _Float16* __restrict__ cprev,
    const _Float16* __restrict__ Xp,
    _Float16* __restrict__ cout, _Float16* __restrict__ hout, _Float16* __restrict__ hsum,
    int n, int gx0, float* __restrict__ fin)
{
    int idx = blockIdx.x * blockDim.x + threadIdx.x;
    int npairs = (n > 1) ? (n >> 1) : 1;
    if (idx >= npairs * 128) return;
    int r = idx >> 7, m8 = (idx & 127) * 8;
    float hs[8];
#pragma unroll
    for (int j = 0; j < 8; ++j) hs[j] = 0.f;
    int pmax = (n > 1) ? 2 : 1;
    for (int t = 0; t < pmax; ++t) {
        int p = 2 * r + t;
        long long node = gx0 + p;
        half8 phi = *(const half8*)&houpre[(long long)p * 3072 + m8];
        half8 pho = *(const half8*)&houpre[(long long)p * 3072 + 1024 + m8];
        half8 phu = *(const half8*)&houpre[(long long)p * 3072 + 2048 + m8];
        half8 pxi = *(const half8*)&Xp[node * 4096 + m8];
        half8 pxo = *(const half8*)&Xp[node * 4096 + 1024 + m8];
        half8 pxu = *(const half8*)&Xp[node * 4096 + 2048 + m8];
        half8 pxf = *(const half8*)&Xp[node * 4096 + 3072 + m8];
        half8 pf0 = *(const half8*)&fpre[(long long)(2 * p) * 1024 + m8];
        half8 pf1 = *(const half8*)&fpre[(long long)(2 * p + 1) * 1024 + m8];
        half8 pc0 = *(const half8*)&cprev[(long long)(2 * p) * 1024 + m8];
        half8 pc1 = *(const half8*)&cprev[(long long)(2 * p + 1) * 1024 + m8];
        float cw[8], hw[8];
#pragma unroll
        for (int j = 0; j < 8; ++j) {
            float i  = sigf((float)phi[j] + (float)pxi[j]);
            float o  = sigf((float)pho[j] + (float)pxo[j]);
            float u  = tanhfast((float)phu[j] + (float)pxu[j]);
            float f0 = sigf((float)pf0[j] + (float)pxf[j]);
            float f1 = sigf((float)pf1[j] + (float)pxf[j]);
            float c = i * u + f0 * (float)pc0[j] + f1 * (float)pc1[j];
            float h = o * tanhfast(c);
            cw[j] = c; hw[j] = h; hs[j] += h;
        }
        if (fin) {                      // lvl0: write [c;h] f32 to d_out
            f32x4 v0 = {cw[0], cw[1], cw[2], cw[3]}, v1 = {cw[4], cw[5], cw[6], cw[7]};
            f32x4 w0 = {hw[0], hw[1], hw[2], hw[3]}, w1 = {hw[4], hw[5], hw[6], hw[7]};
            *(f32x4*)&fin[m8] = v0;            *(f32x4*)&fin[m8 + 4] = v1;
            *(f32x4*)&fin[1024 + m8] = w0;     *(f32x4*)&fin[1024 + m8 + 4] = w1;
        } else {
            half8 cv, hv;
#pragma unroll
            for (int j = 0; j < 8; ++j) { cv[j] = (_Float16)cw[j]; hv[j] = (_Float16)hw[j]; }
            *(half8*)&cout[(long long)p * 1024 + m8] = cv;
            *(half8*)&hout[(long long)p * 1024 + m8] = hv;
        }
    }
    if (!fin) {
        half8 sv;
#pragma unroll
        for (int j = 0; j < 8; ++j) sv[j] = (_Float16)hs[j];
        *(half8*)&hsum[(long long)r * 1024 + m8] = sv;
    }
}

// ---------------------------------------------------------------------------
extern "C" void kernel_launch(void* const* d_in, const int* in_sizes, int n_in,
                              void* d_out, int out_size, void* d_ws, size_t ws_size,
                              hipStream_t stream)
{
    const float* embs = (const float*)d_in[0];
    const float* Wix = (const float*)d_in[1];  const float* bix = (const float*)d_in[2];
    const float* Wih = (const float*)d_in[3];  const float* bih = (const float*)d_in[4];
    const float* Wfx = (const float*)d_in[5];  const float* bfx = (const float*)d_in[6];
    const float* Wfh = (const float*)d_in[7];  const float* bfh = (const float*)d_in[8];
    const float* Wox = (const float*)d_in[9];  const float* box_ = (const float*)d_in[10];
    const float* Woh = (const float*)d_in[11]; const float* boh = (const float*)d_in[12];
    const float* Wux = (const float*)d_in[13]; const float* bux = (const float*)d_in[14];
    const float* Wuh = (const float*)d_in[15]; const float* buh = (const float*)d_in[16];

    char* p = (char*)d_ws;
    auto carve = [&](size_t bytes) -> char* {
        char* r = p; p += (bytes + 255) & ~(size_t)255; return r;
    };
    _Float16* Wiou16 = (_Float16*)carve((size_t)3072 * 1024 * 2);   //   6.3 MB
    _Float16* Wfh16  = (_Float16*)carve((size_t)1024 * 1024 * 2);   //   2.1 MB
    _Float16* Xp     = (_Float16*)carve((size_t)8192 * 4096 * 2);   //  67.1 MB (iou|f)
    _Float16* houpre = (_Float16*)carve((size_t)4096 * 3072 * 2);   //  25.2 MB
    _Float16* fpre   = (_Float16*)carve((size_t)8192 * 1024 * 2);   //  16.8 MB
    _Float16* H_A    = (_Float16*)carve((size_t)8192 * 1024 * 2);   //  16.8 MB
    _Float16* H_B    = (_Float16*)carve((size_t)4096 * 1024 * 2);   //   8.4 MB
    _Float16* HsumA  = (_Float16*)carve((size_t)4096 * 1024 * 2);   //   8.4 MB
    _Float16* HsumB  = (_Float16*)carve((size_t)4096 * 1024 * 2);   //   8.4 MB
    _Float16* Cleaf  = (_Float16*)carve((size_t)8192 * 1024 * 2);   //  16.8 MB
    _Float16* CpingH = (_Float16*)carve((size_t)4096 * 1024 * 2);   //   8.4 MB (fp16 c)
    _Float16* CpongH = (_Float16*)carve((size_t)2048 * 1024 * 2);   //   4.2 MB (fp16 c)
    _Float16* houp4  = (_Float16*)carve((size_t)4 * 64 * 3072 * 2); //   1.5 MB (split-K)
    _Float16* fp4    = (_Float16*)carve((size_t)4 * 128 * 1024 * 2);//   1.0 MB (split-K)
    // total ~192 MB. Aliases (stream-ordered): x16/Bx live in fpre (13.1 MB
    // needed <= 16.8), dead after leaf_fused; fpre first written at lvl12.
    _Float16* x16 = fpre;
    _Float16* Bx  = fpre + (size_t)16384 * XDIM;

    {   // pack
        long long tot = 3072LL * 1024 + 1024LL * 1024 + 16384LL * XDIM + 4096LL * XDIM;
        pack_kernel<<<dim3((int)((tot + 255) / 256)), dim3(256), 0, stream>>>(
            embs, Wix, bix, Wih, bih, Wfx, bfx, Wfh, bfh,
            Wox, box_, Woh, boh, Wux, bux, Wuh, buh,
            Wiou16, Wfh16, x16, Bx);
    }

    // Xp = x[0:8192] @ [Wix;Wox;Wux;Wfx]^T (+biases), 8192x4096, K=320 — one GEMM
    gemm_f16<128, 128, 32><<<dim3(64, 32), dim3(256), 0, stream>>>(
        x16, XDIM, Bx, XDIM, Xp, 4096, XDIM);
    // Leaf level fused GEMM+combine
    leaf_fused<<<dim3(128, 8), dim3(256), 0, stream>>>(x16, Bx, Cleaf, H_A, HsumA);

    const _Float16* cprev = Cleaf;
    _Float16* cbufs[2] = {CpingH, CpongH};
    _Float16* hsums[2] = {HsumA, HsumB};
    int ci = 0, si = 0;
    _Float16* hcur = H_A;
    _Float16* hnext = H_B;

    for (int lvl = 12; lvl >= 0; --lvl) {
        int n = 1 << lvl;
        int npairs = (n > 1) ? (n >> 1) : 1;
        int blocks = (npairs * 128 + 255) / 256;
        float* fin = (lvl == 0) ? (float*)d_out : nullptr;

        if (n >= 1024) {
            int G1 = n / 128, G2 = 2 * n / 128;
            gemm_level<128, 128, 32><<<dim3(G1 * 24 + G2 * 8), dim3(256), 0, stream>>>(
                hsums[si], hcur, Wiou16, Wfh16, houpre, fpre, G1, G2);
            combine_level<<<dim3(blocks), dim3(256), 0, stream>>>(
                houpre, fpre, cprev, Xp, cbufs[ci], hnext, hsums[si ^ 1], n, n - 1, fin);
        } else if (n >= 128) {
            int G1 = n / 128, G2 = 2 * n / 128;
            gemm_level<128, 128, 128><<<dim3(G1 * 24 + G2 * 8), dim3(256), 0, stream>>>(
                hsums[si], hcur, Wiou16, Wfh16, houpre, fpre, G1, G2);
            combine_level<<<dim3(blocks), dim3(256), 0, stream>>>(
                houpre, fpre, cprev, Xp, cbufs[ci], hnext, hsums[si ^ 1], n, n - 1, fin);
        } else {
            // n <= 64: split-K (S=4, one K-step per block, 128 blocks)
            tail_sk<<<dim3(128), dim3(256), 0, stream>>>(
                hsums[si], hcur, Wiou16, Wfh16, houp4, fp4);
            combine_tail_sk<<<dim3(blocks), dim3(256), 0, stream>>>(
                houp4, fp4, cprev, Xp, cbufs[ci], hnext, hsums[si ^ 1], n, n - 1, fin);
        }

        cprev = cbufs[ci];
        ci ^= 1; si ^= 1;
        _Float16* tmp = hcur; hcur = hnext; hnext = tmp;
    }
}

// Round 13
// 441.247 us; speedup vs baseline: 1.0526x; 1.0526x over previous
//
#include <hip/hip_runtime.h>
#include <hip/hip_bf16.h>

#define IN_DIM 300
#define XDIM   320      // x row padded: 300 vals + bias-one at col 300 + zeros
#define MEM    1024
#define NTREE  16383

typedef _Float16 half8 __attribute__((ext_vector_type(8)));
typedef float    f32x4 __attribute__((ext_vector_type(4)));

__device__ __forceinline__ float sigf(float x) { return 1.0f / (1.0f + __expf(-x)); }
__device__ __forceinline__ float tanhfast(float x) { return 2.0f / (1.0f + __expf(-2.0f * x)) - 1.0f; }

#define GLOAD_LDS16(g, l) \
    __builtin_amdgcn_global_load_lds((const __attribute__((address_space(1))) void*)(g), \
                                     (__attribute__((address_space(3))) void*)(l), 16, 0, 0)

// ---------------------------------------------------------------------------
// Pack (one-time): Wiou16 = [Wih;Woh;Wuh] (3072x1024 fp16), Wfh16 (1024x1024),
// x16 (16384x320: [x | 1.0 | 0...]), Bx (4096x320: [Wgx | bgx+bgh | 0...],
// rows g=i,o,u,f).
// ---------------------------------------------------------------------------
__global__ void pack_kernel(
    const float* __restrict__ embs,
    const float* __restrict__ Wix, const float* __restrict__ bix,
    const float* __restrict__ Wih, const float* __restrict__ bih,
    const float* __restrict__ Wfx, const float* __restrict__ bfx,
    const float* __restrict__ Wfh, const float* __restrict__ bfh,
    const float* __restrict__ Wox, const float* __restrict__ box_,
    const float* __restrict__ Woh, const float* __restrict__ boh,
    const float* __restrict__ Wux, const float* __restrict__ bux,
    const float* __restrict__ Wuh, const float* __restrict__ buh,
    _Float16* __restrict__ Wiou16, _Float16* __restrict__ Wfh16,
    _Float16* __restrict__ x16, _Float16* __restrict__ Bx)
{
    long long idx = (long long)blockIdx.x * blockDim.x + threadIdx.x;
    const long long n_wiou = 3072LL * 1024;
    const long long n_wfh  = 1024LL * 1024;
    const long long n_x    = 16384LL * XDIM;
    const long long n_bx   = 4096LL * XDIM;
    if (idx < n_wiou) {
        int m = (int)(idx >> 10), k = (int)(idx & 1023);
        int g = m >> 10, mm = m & 1023;
        const float* W = (g == 0) ? Wih : (g == 1) ? Woh : Wuh;
        Wiou16[idx] = (_Float16)W[(long long)mm * MEM + k];
        return;
    }
    idx -= n_wiou;
    if (idx < n_wfh) {
        Wfh16[idx] = (_Float16)Wfh[idx];
        return;
    }
    idx -= n_wfh;
    if (idx < n_x) {
        int node = (int)(idx / XDIM), j = (int)(idx % XDIM);
        float v = 0.f;
        if (node < NTREE) {
            if (j < IN_DIM) v = embs[(long long)node * IN_DIM + j];
            else if (j == IN_DIM) v = 1.0f;
        }
        x16[idx] = (_Float16)v;
        return;
    }
    idx -= n_x;
    if (idx < n_bx) {
        int r = (int)(idx / XDIM), j = (int)(idx % XDIM);
        int g = r >> 10, mm = r & 1023;
        const float* Wx = (g == 0) ? Wix : (g == 1) ? Wox : (g == 2) ? Wux : Wfx;
        const float* b1 = (g == 0) ? bix : (g == 1) ? box_ : (g == 2) ? bux : bfx;
        const float* b2 = (g == 0) ? bih : (g == 1) ? boh : (g == 2) ? buh : bfh;
        float v = 0.f;
        if (j < IN_DIM) v = Wx[(long long)mm * IN_DIM + j];
        else if (j == IN_DIM) v = b1[mm] + b2[mm];
        Bx[idx] = (_Float16)v;
    }
}

// ---------------------------------------------------------------------------
// GEMM tile core: C(BMxBN) = A(BMxK) * B(BNxK)^T. fp16 in / f32 MFMA / fp16
// out. 4 waves (2x2). Single-buffered LDS, m97 2-barrier structure (proven
// fastest at 2-phase: r2 63.7us vs r3-dbuf 79.6 / r5-BK64 69.3). XOR swizzle
// slot arithmetic (rule-21-compliant). BODY UNCHANGED since r6 — the hot
// <128,128,32> instantiation's codegen (VGPR 84) is the canary.
// ---------------------------------------------------------------------------
template<int BM, int BN, int BK>
__device__ __forceinline__ void gemm_tile(
    const _Float16* __restrict__ A, int lda,
    const _Float16* __restrict__ B, int ldb,
    _Float16* __restrict__ C, int ldc, int K,
    _Float16* ldsA, _Float16* ldsB)
{
    constexpr int FM = BM / 32, FN = BN / 32;
    constexpr int CPR = BK / 8, SWM = CPR - 1;
    constexpr int ACH = BM * BK / 2048, BCH = BN * BK / 2048;

    int tid = threadIdx.x, wave = tid >> 6, lane = tid & 63;
    int wr = (wave >> 1) * (BM / 2), wc = (wave & 1) * (BN / 2);
    int kq = (lane >> 4) * 8, rs = lane & 15;
    f32x4 acc[FM][FN] = {};

    for (int k0 = 0; k0 < K; k0 += BK) {
#pragma unroll
        for (int j = 0; j < ACH; ++j) {
            int c = j * 256 + tid;
            int row = c / CPR;
            int s = (c ^ row) & SWM;
            GLOAD_LDS16(A + (long long)row * lda + k0 + s * 8,
                        &ldsA[(j * 256 + wave * 64) * 8]);
        }
#pragma unroll
        for (int j = 0; j < BCH; ++j) {
            int c = j * 256 + tid;
            int row = c / CPR;
            int s = (c ^ row) & SWM;
            GLOAD_LDS16(B + (long long)row * ldb + k0 + s * 8,
                        &ldsB[(j * 256 + wave * 64) * 8]);
        }
        __syncthreads();
#pragma unroll
        for (int kk = 0; kk < BK; kk += 32) {
            half8 a[FM], b[FN];
#pragma unroll
            for (int i = 0; i < FM; ++i) {
                int r = wr + i * 16 + rs;
                int s = ((kk + kq) >> 3) ^ (r & SWM);
                a[i] = *(const half8*)&ldsA[r * BK + s * 8];
            }
#pragma unroll
            for (int i = 0; i < FN; ++i) {
                int r = wc + i * 16 + rs;
                int s = ((kk + kq) >> 3) ^ (r & SWM);
                b[i] = *(const half8*)&ldsB[r * BK + s * 8];
            }
#pragma unroll
            for (int mi = 0; mi < FM; ++mi)
#pragma unroll
                for (int ni = 0; ni < FN; ++ni)
                    acc[mi][ni] = __builtin_amdgcn_mfma_f32_16x16x32_f16(a[mi], b[ni], acc[mi][ni], 0, 0, 0);
        }
        __syncthreads();
    }
    // C/D layout: col = lane&15, row = (lane>>4)*4 + reg  [m89-verified]
    int crb = wr + (lane >> 4) * 4, ccb = wc + rs;
#pragma unroll
    for (int mi = 0; mi < FM; ++mi)
#pragma unroll
        for (int i = 0; i < 4; ++i) {
            long long r = crb + mi * 16 + i;
#pragma unroll
            for (int ni = 0; ni < FN; ++ni)
                C[r * ldc + ccb + ni * 16] = (_Float16)acc[mi][ni][i];
        }
}

template<int BM, int BN, int BK>
__global__ __launch_bounds__(256) void gemm_f16(
    const _Float16* __restrict__ A, int lda,
    const _Float16* __restrict__ B, int ldb,
    _Float16* __restrict__ C, int ldc, int K)
{
    __shared__ __align__(16) _Float16 ldsA[BM * BK];
    __shared__ __align__(16) _Float16 ldsB[BN * BK];
    gemm_tile<BM, BN, BK>(A + (long long)blockIdx.x * BM * lda, lda,
                          B + (long long)blockIdx.y * BN * ldb, ldb,
                          C + (long long)blockIdx.x * BM * ldc + (long long)blockIdx.y * BN,
                          ldc, K, ldsA, ldsB);
}

// Fused per-level GEMM: part1 = hsum @ Wiou^T (n x 3072), part2 = H @ Wfh^T
// (2n x 1024). Both K=1024. BK=32 for big levels (16KB LDS, occupancy-best);
// BK=128/256 for small levels (serial K-step COUNT dominates at tiny grids).
// r13: XCD-aware chunked blockIdx swizzle (T1) — consecutive blocks share a
// weight panel (same nb); default round-robin replicates each panel across
// all 8 XCD L2s (FETCH 45MB vs ~19MB working set). Chunked remap co-locates
// same-panel blocks on one XCD. All gemm_level grids are %8 == 0.
template<int BM1, int BM2, int BK>
__global__ __launch_bounds__(256) void gemm_level(
    const _Float16* __restrict__ Hsum, const _Float16* __restrict__ Hc,
    const _Float16* __restrict__ Wiou, const _Float16* __restrict__ Wf,
    _Float16* __restrict__ houpre, _Float16* __restrict__ fpre,
    int G1, int G2)
{
    constexpr int BMX = (BM1 > BM2) ? BM1 : BM2;
    __shared__ __align__(16) _Float16 ldsA[BMX * BK];
    __shared__ __align__(16) _Float16 ldsB[128 * BK];
    int q = (int)gridDim.x >> 3;                       // grid % 8 == 0
    int bx = ((int)blockIdx.x & 7) * q + ((int)blockIdx.x >> 3);
    if (bx < G1 * 24) {
        int nb = bx / G1, mb = bx % G1;
        gemm_tile<BM1, 128, BK>(Hsum + (long long)mb * BM1 * 1024, 1024,
                                Wiou + (long long)nb * 128 * 1024, 1024,
                                houpre + (long long)mb * BM1 * 3072 + nb * 128, 3072,
                                1024, ldsA, ldsB);
    } else {
        int b2 = bx - G1 * 24;
        int nb = b2 / G2, mb = b2 % G2;
        gemm_tile<BM2, 128, BK>(Hc + (long long)mb * BM2 * 1024, 1024,
                                Wf + (long long)nb * 128 * 1024, 1024,
                                fpre + (long long)mb * BM2 * 1024 + nb * 128, 1024,
                                1024, ldsA, ldsB);
    }
}

// ---------------------------------------------------------------------------
// Leaf fused GEMM+combine: tile 64 leaves x 128 cols, 3 gate accumulators
// (i,o,u), K=320, single-buffered (28 KB LDS). Writes cleaf/h/hsum.
// ---------------------------------------------------------------------------
__global__ __launch_bounds__(256) void leaf_fused(
    const _Float16* __restrict__ x16, const _Float16* __restrict__ Bx,
    _Float16* __restrict__ cleaf, _Float16* __restrict__ hleaf,
    _Float16* __restrict__ hsum)
{
    constexpr int BK = 32, CPR = 4, SWM = 3;
    __shared__ __align__(16) _Float16 lA[64 * BK];
    __shared__ __align__(16) _Float16 lB[384 * BK];
    int tid = threadIdx.x, wave = tid >> 6, lane = tid & 63;
    int kq = (lane >> 4) * 8, rs = lane & 15;
    int wr = (wave >> 1) * 32, wc = (wave & 1) * 64;
    int m0 = blockIdx.x * 64, c0 = blockIdx.y * 128;
    const _Float16* A = x16 + (size_t)(8191 + m0) * XDIM;

    f32x4 acc[3][2][4] = {};
    for (int t = 0; t < 10; ++t) {     // K = 320
        int k0 = t * BK;
        {   // A: 256 chunks, 1/thread
            int c = tid, row = c / CPR, s = (c ^ row) & SWM;
            GLOAD_LDS16(A + (long long)row * XDIM + k0 + s * 8, &lA[(wave * 64) * 8]);
        }
#pragma unroll
        for (int j = 0; j < 6; ++j) {   // B: 1536 chunks (3 gate tiles x 128)
            int c = j * 256 + tid;
            int row = c / CPR, s = (c ^ row) & SWM;
            int g = row >> 7, rr = row & 127;
            GLOAD_LDS16(Bx + (long long)(g * 1024 + c0 + rr) * XDIM + k0 + s * 8,
                        &lB[(j * 256 + wave * 64) * 8]);
        }
        __syncthreads();
        half8 a[2], b[3][4];
#pragma unroll
        for (int mi = 0; mi < 2; ++mi) {
            int r = wr + mi * 16 + rs;
            int s = (kq >> 3) ^ (r & SWM);
            a[mi] = *(const half8*)&lA[r * BK + s * 8];
        }
#pragma unroll
        for (int g = 0; g < 3; ++g)
#pragma unroll
            for (int nj = 0; nj < 4; ++nj) {
                int r = g * 128 + wc + nj * 16 + rs;
                int s = (kq >> 3) ^ (r & SWM);
                b[g][nj] = *(const half8*)&lB[r * BK + s * 8];
            }
#pragma unroll
        for (int g = 0; g < 3; ++g)
#pragma unroll
            for (int mi = 0; mi < 2; ++mi)
#pragma unroll
                for (int nj = 0; nj < 4; ++nj)
                    acc[g][mi][nj] = __builtin_amdgcn_mfma_f32_16x16x32_f16(a[mi], b[g][nj], acc[g][mi][nj], 0, 0, 0);
        __syncthreads();
    }
    int lrb = wr + (lane >> 4) * 4;
#pragma unroll
    for (int mi = 0; mi < 2; ++mi)
#pragma unroll
        for (int nj = 0; nj < 4; ++nj) {
            int col = c0 + wc + nj * 16 + rs;
            float hpair = 0.f;
#pragma unroll
            for (int i = 0; i < 4; ++i) {
                long long l = m0 + lrb + mi * 16 + i;
                float cc = sigf(acc[0][mi][nj][i]) * tanhfast(acc[2][mi][nj][i]);
                float hh = sigf(acc[1][mi][nj][i]) * tanhfast(cc);
                cleaf[l * 1024 + col] = (_Float16)cc;
                hleaf[l * 1024 + col] = (_Float16)hh;
                if (i & 1) hsum[(l >> 1) * 1024 + col] = (_Float16)(hpair + hh);
                else hpair = hh;
            }
        }
}

// ---------------------------------------------------------------------------
// Combine: gates from houpre + Xp(iou cols 0..3071), f per child from fpre +
// Xp(col 3072+), c = i*u + f0*c0 + f1*c1, h = o*tanh(c). c stored fp16.
// Emits c/h/hsum; at lvl0 writes d_out = [c;h] f32 from registers instead.
// ---------------------------------------------------------------------------
__global__ void combine_level(
    const _Float16* __restrict__ houpre, const _Float16* __restrict__ fpre,
    const _Float16* __restrict__ cprev,
    const _Float16* __restrict__ Xp,
    _Float16* __restrict__ cout, _Float16* __restrict__ hout, _Float16* __restrict__ hsum,
    int n, int gx0, float* __restrict__ fin)
{
    int idx = blockIdx.x * blockDim.x + threadIdx.x;
    int npairs = (n > 1) ? (n >> 1) : 1;
    if (idx >= npairs * 128) return;
    int r = idx >> 7, m8 = (idx & 127) * 8;
    float hs[8];
#pragma unroll
    for (int j = 0; j < 8; ++j) hs[j] = 0.f;
    int pmax = (n > 1) ? 2 : 1;
    for (int t = 0; t < pmax; ++t) {
        int p = 2 * r + t;
        long long node = gx0 + p;
        half8 phi = *(const half8*)&houpre[(long long)p * 3072 + m8];
        half8 pho = *(const half8*)&houpre[(long long)p * 3072 + 1024 + m8];
        half8 phu = *(const half8*)&houpre[(long long)p * 3072 + 2048 + m8];
        half8 pxi = *(const half8*)&Xp[node * 4096 + m8];
        half8 pxo = *(const half8*)&Xp[node * 4096 + 1024 + m8];
        half8 pxu = *(const half8*)&Xp[node * 4096 + 2048 + m8];
        half8 pxf = *(const half8*)&Xp[node * 4096 + 3072 + m8];
        half8 pf0 = *(const half8*)&fpre[(long long)(2 * p) * 1024 + m8];
        half8 pf1 = *(const half8*)&fpre[(long long)(2 * p + 1) * 1024 + m8];
        half8 pc0 = *(const half8*)&cprev[(long long)(2 * p) * 1024 + m8];
        half8 pc1 = *(const half8*)&cprev[(long long)(2 * p + 1) * 1024 + m8];
        float cw[8], hw[8];
#pragma unroll
        for (int j = 0; j < 8; ++j) {
            float i  = sigf((float)phi[j] + (float)pxi[j]);
            float o  = sigf((float)pho[j] + (float)pxo[j]);
            float u  = tanhfast((float)phu[j] + (float)pxu[j]);
            float f0 = sigf((float)pf0[j] + (float)pxf[j]);
            float f1 = sigf((float)pf1[j] + (float)pxf[j]);
            float c = i * u + f0 * (float)pc0[j] + f1 * (float)pc1[j];
            float h = o * tanhfast(c);
            cw[j] = c; hw[j] = h; hs[j] += h;
        }
        if (fin) {                      // lvl0: write [c;h] f32 to d_out
            f32x4 v0 = {cw[0], cw[1], cw[2], cw[3]}, v1 = {cw[4], cw[5], cw[6], cw[7]};
            f32x4 w0 = {hw[0], hw[1], hw[2], hw[3]}, w1 = {hw[4], hw[5], hw[6], hw[7]};
            *(f32x4*)&fin[m8] = v0;            *(f32x4*)&fin[m8 + 4] = v1;
            *(f32x4*)&fin[1024 + m8] = w0;     *(f32x4*)&fin[1024 + m8 + 4] = w1;
        } else {
            half8 cv, hv;
#pragma unroll
            for (int j = 0; j < 8; ++j) { cv[j] = (_Float16)cw[j]; hv[j] = (_Float16)hw[j]; }
            *(half8*)&cout[(long long)p * 1024 + m8] = cv;
            *(half8*)&hout[(long long)p * 1024 + m8] = hv;
        }
    }
    if (!fin) {
        half8 sv;
#pragma unroll
        for (int j = 0; j < 8; ++j) sv[j] = (_Float16)hs[j];
        *(half8*)&hsum[(long long)r * 1024 + m8] = sv;
    }
}

// ---------------------------------------------------------------------------
extern "C" void kernel_launch(void* const* d_in, const int* in_sizes, int n_in,
                              void* d_out, int out_size, void* d_ws, size_t ws_size,
                              hipStream_t stream)
{
    const float* embs = (const float*)d_in[0];
    const float* Wix = (const float*)d_in[1];  const float* bix = (const float*)d_in[2];
    const float* Wih = (const float*)d_in[3];  const float* bih = (const float*)d_in[4];
    const float* Wfx = (const float*)d_in[5];  const float* bfx = (const float*)d_in[6];
    const float* Wfh = (const float*)d_in[7];  const float* bfh = (const float*)d_in[8];
    const float* Wox = (const float*)d_in[9];  const float* box_ = (const float*)d_in[10];
    const float* Woh = (const float*)d_in[11]; const float* boh = (const float*)d_in[12];
    const float* Wux = (const float*)d_in[13]; const float* bux = (const float*)d_in[14];
    const float* Wuh = (const float*)d_in[15]; const float* buh = (const float*)d_in[16];

    char* p = (char*)d_ws;
    auto carve = [&](size_t bytes) -> char* {
        char* r = p; p += (bytes + 255) & ~(size_t)255; return r;
    };
    _Float16* Wiou16 = (_Float16*)carve((size_t)3072 * 1024 * 2);   //   6.3 MB
    _Float16* Wfh16  = (_Float16*)carve((size_t)1024 * 1024 * 2);   //   2.1 MB
    _Float16* Xp     = (_Float16*)carve((size_t)8192 * 4096 * 2);   //  67.1 MB (iou|f)
    _Float16* houpre = (_Float16*)carve((size_t)4096 * 3072 * 2);   //  25.2 MB
    _Float16* fpre   = (_Float16*)carve((size_t)8192 * 1024 * 2);   //  16.8 MB
    _Float16* H_A    = (_Float16*)carve((size_t)8192 * 1024 * 2);   //  16.8 MB
    _Float16* H_B    = (_Float16*)carve((size_t)4096 * 1024 * 2);   //   8.4 MB
    _Float16* HsumA  = (_Float16*)carve((size_t)4096 * 1024 * 2);   //   8.4 MB
    _Float16* HsumB  = (_Float16*)carve((size_t)4096 * 1024 * 2);   //   8.4 MB
    _Float16* Cleaf  = (_Float16*)carve((size_t)8192 * 1024 * 2);   //  16.8 MB
    _Float16* CpingH = (_Float16*)carve((size_t)4096 * 1024 * 2);   //   8.4 MB (fp16 c)
    _Float16* CpongH = (_Float16*)carve((size_t)2048 * 1024 * 2);   //   4.2 MB (fp16 c)
    // total ~189 MB. Aliases (stream-ordered): x16/Bx live in fpre (13.1 MB
    // needed <= 16.8), dead after leaf_fused; fpre first written at lvl12.
    _Float16* x16 = fpre;
    _Float16* Bx  = fpre + (size_t)16384 * XDIM;

    {   // pack
        long long tot = 3072LL * 1024 + 1024LL * 1024 + 16384LL * XDIM + 4096LL * XDIM;
        pack_kernel<<<dim3((int)((tot + 255) / 256)), dim3(256), 0, stream>>>(
            embs, Wix, bix, Wih, bih, Wfx, bfx, Wfh, bfh,
            Wox, box_, Woh, boh, Wux, bux, Wuh, buh,
            Wiou16, Wfh16, x16, Bx);
    }

    // Xp = x[0:8192] @ [Wix;Wox;Wux;Wfx]^T (+biases), 8192x4096, K=320 — one GEMM
    gemm_f16<128, 128, 32><<<dim3(64, 32), dim3(256), 0, stream>>>(
        x16, XDIM, Bx, XDIM, Xp, 4096, XDIM);
    // Leaf level fused GEMM+combine
    leaf_fused<<<dim3(128, 8), dim3(256), 0, stream>>>(x16, Bx, Cleaf, H_A, HsumA);

    const _Float16* cprev = Cleaf;
    _Float16* cbufs[2] = {CpingH, CpongH};
    _Float16* hsums[2] = {HsumA, HsumB};
    int ci = 0, si = 0;
    _Float16* hcur = H_A;
    _Float16* hnext = H_B;

    for (int lvl = 12; lvl >= 0; --lvl) {
        int n = 1 << lvl;
        int G1, G2;
        if (n >= 1024) {
            G1 = n / 128; G2 = 2 * n / 128;
            gemm_level<128, 128, 32><<<dim3(G1 * 24 + G2 * 8), dim3(256), 0, stream>>>(
                hsums[si], hcur, Wiou16, Wfh16, houpre, fpre, G1, G2);
        } else if (n >= 128) {
            G1 = n / 128; G2 = 2 * n / 128;
            gemm_level<128, 128, 128><<<dim3(G1 * 24 + G2 * 8), dim3(256), 0, stream>>>(
                hsums[si], hcur, Wiou16, Wfh16, houpre, fpre, G1, G2);
        } else if (n == 64) {
            // BK=256: 4 serial K-steps (latency-bound regime, step count rules)
            G1 = 1; G2 = 1;
            gemm_level<64, 128, 256><<<dim3(G1 * 24 + G2 * 8), dim3(256), 0, stream>>>(
                hsums[si], hcur, Wiou16, Wfh16, houpre, fpre, G1, G2);
        } else {
            G1 = 1; G2 = 1;
            gemm_level<64, 64, 256><<<dim3(G1 * 24 + G2 * 8), dim3(256), 0, stream>>>(
                hsums[si], hcur, Wiou16, Wfh16, houpre, fpre, G1, G2);
        }

        int npairs = (n > 1) ? (n >> 1) : 1;
        int blocks = (npairs * 128 + 255) / 256;
        float* fin = (lvl == 0) ? (float*)d_out : nullptr;
        combine_level<<<dim3(blocks), dim3(256), 0, stream>>>(
            houpre, fpre, cprev, Xp, cbufs[ci], hnext, hsums[si ^ 1], n, n - 1, fin);

        cprev = cbufs[ci];
        ci ^= 1; si ^= 1;
        _Float16* tmp = hcur; hcur = hnext; hnext = tmp;
    }
}

// Round 14
// 434.731 us; speedup vs baseline: 1.0684x; 1.0150x over previous
//
#include <hip/hip_runtime.h>
#include <hip/hip_bf16.h>

#define IN_DIM 300
#define XDIM   320      // x row padded: 300 vals + bias-one at col 300 + zeros
#define MEM    1024
#define NTREE  16383

typedef _Float16 half8 __attribute__((ext_vector_type(8)));
typedef float    f32x4 __attribute__((ext_vector_type(4)));

__device__ __forceinline__ float sigf(float x) { return 1.0f / (1.0f + __expf(-x)); }
__device__ __forceinline__ float tanhfast(float x) { return 2.0f / (1.0f + __expf(-2.0f * x)) - 1.0f; }

#define GLOAD_LDS16(g, l) \
    __builtin_amdgcn_global_load_lds((const __attribute__((address_space(1))) void*)(g), \
                                     (__attribute__((address_space(3))) void*)(l), 16, 0, 0)

// ---------------------------------------------------------------------------
// Pack (one-time): Wiou16 = [Wih;Woh;Wuh] (3072x1024 fp16), Wfh16 (1024x1024),
// x16 (16384x320: [x | 1.0 | 0...]), Bx (4096x320: [Wgx | bgx+bgh | 0...],
// rows g=i,o,u,f).
// ---------------------------------------------------------------------------
__global__ void pack_kernel(
    const float* __restrict__ embs,
    const float* __restrict__ Wix, const float* __restrict__ bix,
    const float* __restrict__ Wih, const float* __restrict__ bih,
    const float* __restrict__ Wfx, const float* __restrict__ bfx,
    const float* __restrict__ Wfh, const float* __restrict__ bfh,
    const float* __restrict__ Wox, const float* __restrict__ box_,
    const float* __restrict__ Woh, const float* __restrict__ boh,
    const float* __restrict__ Wux, const float* __restrict__ bux,
    const float* __restrict__ Wuh, const float* __restrict__ buh,
    _Float16* __restrict__ Wiou16, _Float16* __restrict__ Wfh16,
    _Float16* __restrict__ x16, _Float16* __restrict__ Bx)
{
    long long idx = (long long)blockIdx.x * blockDim.x + threadIdx.x;
    const long long n_wiou = 3072LL * 1024;
    const long long n_wfh  = 1024LL * 1024;
    const long long n_x    = 16384LL * XDIM;
    const long long n_bx   = 4096LL * XDIM;
    if (idx < n_wiou) {
        int m = (int)(idx >> 10), k = (int)(idx & 1023);
        int g = m >> 10, mm = m & 1023;
        const float* W = (g == 0) ? Wih : (g == 1) ? Woh : Wuh;
        Wiou16[idx] = (_Float16)W[(long long)mm * MEM + k];
        return;
    }
    idx -= n_wiou;
    if (idx < n_wfh) {
        Wfh16[idx] = (_Float16)Wfh[idx];
        return;
    }
    idx -= n_wfh;
    if (idx < n_x) {
        int node = (int)(idx / XDIM), j = (int)(idx % XDIM);
        float v = 0.f;
        if (node < NTREE) {
            if (j < IN_DIM) v = embs[(long long)node * IN_DIM + j];
            else if (j == IN_DIM) v = 1.0f;
        }
        x16[idx] = (_Float16)v;
        return;
    }
    idx -= n_x;
    if (idx < n_bx) {
        int r = (int)(idx / XDIM), j = (int)(idx % XDIM);
        int g = r >> 10, mm = r & 1023;
        const float* Wx = (g == 0) ? Wix : (g == 1) ? Wox : (g == 2) ? Wux : Wfx;
        const float* b1 = (g == 0) ? bix : (g == 1) ? box_ : (g == 2) ? bux : bfx;
        const float* b2 = (g == 0) ? bih : (g == 1) ? boh : (g == 2) ? buh : bfh;
        float v = 0.f;
        if (j < IN_DIM) v = Wx[(long long)mm * IN_DIM + j];
        else if (j == IN_DIM) v = b1[mm] + b2[mm];
        Bx[idx] = (_Float16)v;
    }
}

// ---------------------------------------------------------------------------
// GEMM tile core: C(BMxBN) = A(BMxK) * B(BNxK)^T. fp16 in / f32 MFMA / fp16
// out. 4 waves (2x2). Single-buffered LDS, m97 2-barrier structure (proven
// fastest at 2-phase: r2 63.7us vs r3-dbuf 79.6 / r5-BK64 69.3). XOR swizzle
// slot arithmetic (rule-21-compliant). BODY UNCHANGED since r6 — the hot
// <128,128,32> instantiation's codegen (VGPR 84) is the canary.
// ---------------------------------------------------------------------------
template<int BM, int BN, int BK>
__device__ __forceinline__ void gemm_tile(
    const _Float16* __restrict__ A, int lda,
    const _Float16* __restrict__ B, int ldb,
    _Float16* __restrict__ C, int ldc, int K,
    _Float16* ldsA, _Float16* ldsB)
{
    constexpr int FM = BM / 32, FN = BN / 32;
    constexpr int CPR = BK / 8, SWM = CPR - 1;
    constexpr int ACH = BM * BK / 2048, BCH = BN * BK / 2048;

    int tid = threadIdx.x, wave = tid >> 6, lane = tid & 63;
    int wr = (wave >> 1) * (BM / 2), wc = (wave & 1) * (BN / 2);
    int kq = (lane >> 4) * 8, rs = lane & 15;
    f32x4 acc[FM][FN] = {};

    for (int k0 = 0; k0 < K; k0 += BK) {
#pragma unroll
        for (int j = 0; j < ACH; ++j) {
            int c = j * 256 + tid;
            int row = c / CPR;
            int s = (c ^ row) & SWM;
            GLOAD_LDS16(A + (long long)row * lda + k0 + s * 8,
                        &ldsA[(j * 256 + wave * 64) * 8]);
        }
#pragma unroll
        for (int j = 0; j < BCH; ++j) {
            int c = j * 256 + tid;
            int row = c / CPR;
            int s = (c ^ row) & SWM;
            GLOAD_LDS16(B + (long long)row * ldb + k0 + s * 8,
                        &ldsB[(j * 256 + wave * 64) * 8]);
        }
        __syncthreads();
#pragma unroll
        for (int kk = 0; kk < BK; kk += 32) {
            half8 a[FM], b[FN];
#pragma unroll
            for (int i = 0; i < FM; ++i) {
                int r = wr + i * 16 + rs;
                int s = ((kk + kq) >> 3) ^ (r & SWM);
                a[i] = *(const half8*)&ldsA[r * BK + s * 8];
            }
#pragma unroll
            for (int i = 0; i < FN; ++i) {
                int r = wc + i * 16 + rs;
                int s = ((kk + kq) >> 3) ^ (r & SWM);
                b[i] = *(const half8*)&ldsB[r * BK + s * 8];
            }
#pragma unroll
            for (int mi = 0; mi < FM; ++mi)
#pragma unroll
                for (int ni = 0; ni < FN; ++ni)
                    acc[mi][ni] = __builtin_amdgcn_mfma_f32_16x16x32_f16(a[mi], b[ni], acc[mi][ni], 0, 0, 0);
        }
        __syncthreads();
    }
    // C/D layout: col = lane&15, row = (lane>>4)*4 + reg  [m89-verified]
    int crb = wr + (lane >> 4) * 4, ccb = wc + rs;
#pragma unroll
    for (int mi = 0; mi < FM; ++mi)
#pragma unroll
        for (int i = 0; i < 4; ++i) {
            long long r = crb + mi * 16 + i;
#pragma unroll
            for (int ni = 0; ni < FN; ++ni)
                C[r * ldc + ccb + ni * 16] = (_Float16)acc[mi][ni][i];
        }
}

template<int BM, int BN, int BK>
__global__ __launch_bounds__(256) void gemm_f16(
    const _Float16* __restrict__ A, int lda,
    const _Float16* __restrict__ B, int ldb,
    _Float16* __restrict__ C, int ldc, int K)
{
    __shared__ __align__(16) _Float16 ldsA[BM * BK];
    __shared__ __align__(16) _Float16 ldsB[BN * BK];
    gemm_tile<BM, BN, BK>(A + (long long)blockIdx.x * BM * lda, lda,
                          B + (long long)blockIdx.y * BN * ldb, ldb,
                          C + (long long)blockIdx.x * BM * ldc + (long long)blockIdx.y * BN,
                          ldc, K, ldsA, ldsB);
}

// Fused per-level GEMM: part1 = hsum @ Wiou^T (n x 3072), part2 = H @ Wfh^T
// (2n x 1024). Both K=1024. BK=32 for the biggest levels (16KB LDS,
// occupancy-best at >=640 blocks); BK=128 for n<=1024 (serial K-step COUNT
// dominates below ~2 blocks/CU — r14 moved the threshold from n>=1024 to
// n>=2048: lvl-10's 320-block grid is the low-occupancy regime);
// BK=256 for n<=64 (4 K-steps). r13's XCD swizzle REVERTED (FETCH doubled:
// each XCD chunk spanned all mb -> full-A re-fetch per XCD; default
// round-robin is already within 1.36x of minimal fetch).
template<int BM1, int BM2, int BK>
__global__ __launch_bounds__(256) void gemm_level(
    const _Float16* __restrict__ Hsum, const _Float16* __restrict__ Hc,
    const _Float16* __restrict__ Wiou, const _Float16* __restrict__ Wf,
    _Float16* __restrict__ houpre, _Float16* __restrict__ fpre,
    int G1, int G2)
{
    constexpr int BMX = (BM1 > BM2) ? BM1 : BM2;
    __shared__ __align__(16) _Float16 ldsA[BMX * BK];
    __shared__ __align__(16) _Float16 ldsB[128 * BK];
    int bx = blockIdx.x;
    if (bx < G1 * 24) {
        int nb = bx / G1, mb = bx % G1;
        gemm_tile<BM1, 128, BK>(Hsum + (long long)mb * BM1 * 1024, 1024,
                                Wiou + (long long)nb * 128 * 1024, 1024,
                                houpre + (long long)mb * BM1 * 3072 + nb * 128, 3072,
                                1024, ldsA, ldsB);
    } else {
        int b2 = bx - G1 * 24;
        int nb = b2 / G2, mb = b2 % G2;
        gemm_tile<BM2, 128, BK>(Hc + (long long)mb * BM2 * 1024, 1024,
                                Wf + (long long)nb * 128 * 1024, 1024,
                                fpre + (long long)mb * BM2 * 1024 + nb * 128, 1024,
                                1024, ldsA, ldsB);
    }
}

// ---------------------------------------------------------------------------
// Leaf fused GEMM+combine: tile 64 leaves x 128 cols, 3 gate accumulators
// (i,o,u), K=320, single-buffered (28 KB LDS). Writes cleaf/h/hsum.
// ---------------------------------------------------------------------------
__global__ __launch_bounds__(256) void leaf_fused(
    const _Float16* __restrict__ x16, const _Float16* __restrict__ Bx,
    _Float16* __restrict__ cleaf, _Float16* __restrict__ hleaf,
    _Float16* __restrict__ hsum)
{
    constexpr int BK = 32, CPR = 4, SWM = 3;
    __shared__ __align__(16) _Float16 lA[64 * BK];
    __shared__ __align__(16) _Float16 lB[384 * BK];
    int tid = threadIdx.x, wave = tid >> 6, lane = tid & 63;
    int kq = (lane >> 4) * 8, rs = lane & 15;
    int wr = (wave >> 1) * 32, wc = (wave & 1) * 64;
    int m0 = blockIdx.x * 64, c0 = blockIdx.y * 128;
    const _Float16* A = x16 + (size_t)(8191 + m0) * XDIM;

    f32x4 acc[3][2][4] = {};
    for (int t = 0; t < 10; ++t) {     // K = 320
        int k0 = t * BK;
        {   // A: 256 chunks, 1/thread
            int c = tid, row = c / CPR, s = (c ^ row) & SWM;
            GLOAD_LDS16(A + (long long)row * XDIM + k0 + s * 8, &lA[(wave * 64) * 8]);
        }
#pragma unroll
        for (int j = 0; j < 6; ++j) {   // B: 1536 chunks (3 gate tiles x 128)
            int c = j * 256 + tid;
            int row = c / CPR, s = (c ^ row) & SWM;
            int g = row >> 7, rr = row & 127;
            GLOAD_LDS16(Bx + (long long)(g * 1024 + c0 + rr) * XDIM + k0 + s * 8,
                        &lB[(j * 256 + wave * 64) * 8]);
        }
        __syncthreads();
        half8 a[2], b[3][4];
#pragma unroll
        for (int mi = 0; mi < 2; ++mi) {
            int r = wr + mi * 16 + rs;
            int s = (kq >> 3) ^ (r & SWM);
            a[mi] = *(const half8*)&lA[r * BK + s * 8];
        }
#pragma unroll
        for (int g = 0; g < 3; ++g)
#pragma unroll
            for (int nj = 0; nj < 4; ++nj) {
                int r = g * 128 + wc + nj * 16 + rs;
                int s = (kq >> 3) ^ (r & SWM);
                b[g][nj] = *(const half8*)&lB[r * BK + s * 8];
            }
#pragma unroll
        for (int g = 0; g < 3; ++g)
#pragma unroll
            for (int mi = 0; mi < 2; ++mi)
#pragma unroll
                for (int nj = 0; nj < 4; ++nj)
                    acc[g][mi][nj] = __builtin_amdgcn_mfma_f32_16x16x32_f16(a[mi], b[g][nj], acc[g][mi][nj], 0, 0, 0);
        __syncthreads();
    }
    int lrb = wr + (lane >> 4) * 4;
#pragma unroll
    for (int mi = 0; mi < 2; ++mi)
#pragma unroll
        for (int nj = 0; nj < 4; ++nj) {
            int col = c0 + wc + nj * 16 + rs;
            float hpair = 0.f;
#pragma unroll
            for (int i = 0; i < 4; ++i) {
                long long l = m0 + lrb + mi * 16 + i;
                float cc = sigf(acc[0][mi][nj][i]) * tanhfast(acc[2][mi][nj][i]);
                float hh = sigf(acc[1][mi][nj][i]) * tanhfast(cc);
                cleaf[l * 1024 + col] = (_Float16)cc;
                hleaf[l * 1024 + col] = (_Float16)hh;
                if (i & 1) hsum[(l >> 1) * 1024 + col] = (_Float16)(hpair + hh);
                else hpair = hh;
            }
        }
}

// ---------------------------------------------------------------------------
// Combine: gates from houpre + Xp(iou cols 0..3071), f per child from fpre +
// Xp(col 3072+), c = i*u + f0*c0 + f1*c1, h = o*tanh(c). c stored fp16.
// Emits c/h/hsum; at lvl0 writes d_out = [c;h] f32 from registers instead.
// ---------------------------------------------------------------------------
__global__ void combine_level(
    const _Float16* __restrict__ houpre, const _Float16* __restrict__ fpre,
    const _Float16* __restrict__ cprev,
    const _Float16* __restrict__ Xp,
    _Float16* __restrict__ cout, _Float16* __restrict__ hout, _Float16* __restrict__ hsum,
    int n, int gx0, float* __restrict__ fin)
{
    int idx = blockIdx.x * blockDim.x + threadIdx.x;
    int npairs = (n > 1) ? (n >> 1) : 1;
    if (idx >= npairs * 128) return;
    int r = idx >> 7, m8 = (idx & 127) * 8;
    float hs[8];
#pragma unroll
    for (int j = 0; j < 8; ++j) hs[j] = 0.f;
    int pmax = (n > 1) ? 2 : 1;
    for (int t = 0; t < pmax; ++t) {
        int p = 2 * r + t;
        long long node = gx0 + p;
        half8 phi = *(const half8*)&houpre[(long long)p * 3072 + m8];
        half8 pho = *(const half8*)&houpre[(long long)p * 3072 + 1024 + m8];
        half8 phu = *(const half8*)&houpre[(long long)p * 3072 + 2048 + m8];
        half8 pxi = *(const half8*)&Xp[node * 4096 + m8];
        half8 pxo = *(const half8*)&Xp[node * 4096 + 1024 + m8];
        half8 pxu = *(const half8*)&Xp[node * 4096 + 2048 + m8];
        half8 pxf = *(const half8*)&Xp[node * 4096 + 3072 + m8];
        half8 pf0 = *(const half8*)&fpre[(long long)(2 * p) * 1024 + m8];
        half8 pf1 = *(const half8*)&fpre[(long long)(2 * p + 1) * 1024 + m8];
        half8 pc0 = *(const half8*)&cprev[(long long)(2 * p) * 1024 + m8];
        half8 pc1 = *(const half8*)&cprev[(long long)(2 * p + 1) * 1024 + m8];
        float cw[8], hw[8];
#pragma unroll
        for (int j = 0; j < 8; ++j) {
            float i  = sigf((float)phi[j] + (float)pxi[j]);
            float o  = sigf((float)pho[j] + (float)pxo[j]);
            float u  = tanhfast((float)phu[j] + (float)pxu[j]);
            float f0 = sigf((float)pf0[j] + (float)pxf[j]);
            float f1 = sigf((float)pf1[j] + (float)pxf[j]);
            float c = i * u + f0 * (float)pc0[j] + f1 * (float)pc1[j];
            float h = o * tanhfast(c);
            cw[j] = c; hw[j] = h; hs[j] += h;
        }
        if (fin) {                      // lvl0: write [c;h] f32 to d_out
            f32x4 v0 = {cw[0], cw[1], cw[2], cw[3]}, v1 = {cw[4], cw[5], cw[6], cw[7]};
            f32x4 w0 = {hw[0], hw[1], hw[2], hw[3]}, w1 = {hw[4], hw[5], hw[6], hw[7]};
            *(f32x4*)&fin[m8] = v0;            *(f32x4*)&fin[m8 + 4] = v1;
            *(f32x4*)&fin[1024 + m8] = w0;     *(f32x4*)&fin[1024 + m8 + 4] = w1;
        } else {
            half8 cv, hv;
#pragma unroll
            for (int j = 0; j < 8; ++j) { cv[j] = (_Float16)cw[j]; hv[j] = (_Float16)hw[j]; }
            *(half8*)&cout[(long long)p * 1024 + m8] = cv;
            *(half8*)&hout[(long long)p * 1024 + m8] = hv;
        }
    }
    if (!fin) {
        half8 sv;
#pragma unroll
        for (int j = 0; j < 8; ++j) sv[j] = (_Float16)hs[j];
        *(half8*)&hsum[(long long)r * 1024 + m8] = sv;
    }
}

// ---------------------------------------------------------------------------
extern "C" void kernel_launch(void* const* d_in, const int* in_sizes, int n_in,
                              void* d_out, int out_size, void* d_ws, size_t ws_size,
                              hipStream_t stream)
{
    const float* embs = (const float*)d_in[0];
    const float* Wix = (const float*)d_in[1];  const float* bix = (const float*)d_in[2];
    const float* Wih = (const float*)d_in[3];  const float* bih = (const float*)d_in[4];
    const float* Wfx = (const float*)d_in[5];  const float* bfx = (const float*)d_in[6];
    const float* Wfh = (const float*)d_in[7];  const float* bfh = (const float*)d_in[8];
    const float* Wox = (const float*)d_in[9];  const float* box_ = (const float*)d_in[10];
    const float* Woh = (const float*)d_in[11]; const float* boh = (const float*)d_in[12];
    const float* Wux = (const float*)d_in[13]; const float* bux = (const float*)d_in[14];
    const float* Wuh = (const float*)d_in[15]; const float* buh = (const float*)d_in[16];

    char* p = (char*)d_ws;
    auto carve = [&](size_t bytes) -> char* {
        char* r = p; p += (bytes + 255) & ~(size_t)255; return r;
    };
    _Float16* Wiou16 = (_Float16*)carve((size_t)3072 * 1024 * 2);   //   6.3 MB
    _Float16* Wfh16  = (_Float16*)carve((size_t)1024 * 1024 * 2);   //   2.1 MB
    _Float16* Xp     = (_Float16*)carve((size_t)8192 * 4096 * 2);   //  67.1 MB (iou|f)
    _Float16* houpre = (_Float16*)carve((size_t)4096 * 3072 * 2);   //  25.2 MB
    _Float16* fpre   = (_Float16*)carve((size_t)8192 * 1024 * 2);   //  16.8 MB
    _Float16* H_A    = (_Float16*)carve((size_t)8192 * 1024 * 2);   //  16.8 MB
    _Float16* H_B    = (_Float16*)carve((size_t)4096 * 1024 * 2);   //   8.4 MB
    _Float16* HsumA  = (_Float16*)carve((size_t)4096 * 1024 * 2);   //   8.4 MB
    _Float16* HsumB  = (_Float16*)carve((size_t)4096 * 1024 * 2);   //   8.4 MB
    _Float16* Cleaf  = (_Float16*)carve((size_t)8192 * 1024 * 2);   //  16.8 MB
    _Float16* CpingH = (_Float16*)carve((size_t)4096 * 1024 * 2);   //   8.4 MB (fp16 c)
    _Float16* CpongH = (_Float16*)carve((size_t)2048 * 1024 * 2);   //   4.2 MB (fp16 c)
    // total ~189 MB. Aliases (stream-ordered): x16/Bx live in fpre (13.1 MB
    // needed <= 16.8), dead after leaf_fused; fpre first written at lvl12.
    _Float16* x16 = fpre;
    _Float16* Bx  = fpre + (size_t)16384 * XDIM;

    {   // pack
        long long tot = 3072LL * 1024 + 1024LL * 1024 + 16384LL * XDIM + 4096LL * XDIM;
        pack_kernel<<<dim3((int)((tot + 255) / 256)), dim3(256), 0, stream>>>(
            embs, Wix, bix, Wih, bih, Wfx, bfx, Wfh, bfh,
            Wox, box_, Woh, boh, Wux, bux, Wuh, buh,
            Wiou16, Wfh16, x16, Bx);
    }

    // Xp = x[0:8192] @ [Wix;Wox;Wux;Wfx]^T (+biases), 8192x4096, K=320 — one GEMM
    gemm_f16<128, 128, 32><<<dim3(64, 32), dim3(256), 0, stream>>>(
        x16, XDIM, Bx, XDIM, Xp, 4096, XDIM);
    // Leaf level fused GEMM+combine
    leaf_fused<<<dim3(128, 8), dim3(256), 0, stream>>>(x16, Bx, Cleaf, H_A, HsumA);

    const _Float16* cprev = Cleaf;
    _Float16* cbufs[2] = {CpingH, CpongH};
    _Float16* hsums[2] = {HsumA, HsumB};
    int ci = 0, si = 0;
    _Float16* hcur = H_A;
    _Float16* hnext = H_B;

    for (int lvl = 12; lvl >= 0; --lvl) {
        int n = 1 << lvl;
        int G1, G2;
        if (n >= 2048) {
            G1 = n / 128; G2 = 2 * n / 128;
            gemm_level<128, 128, 32><<<dim3(G1 * 24 + G2 * 8), dim3(256), 0, stream>>>(
                hsums[si], hcur, Wiou16, Wfh16, houpre, fpre, G1, G2);
        } else if (n >= 128) {
            G1 = n / 128; G2 = 2 * n / 128;
            gemm_level<128, 128, 128><<<dim3(G1 * 24 + G2 * 8), dim3(256), 0, stream>>>(
                hsums[si], hcur, Wiou16, Wfh16, houpre, fpre, G1, G2);
        } else if (n == 64) {
            // BK=256: 4 serial K-steps (latency-bound regime, step count rules)
            G1 = 1; G2 = 1;
            gemm_level<64, 128, 256><<<dim3(G1 * 24 + G2 * 8), dim3(256), 0, stream>>>(
                hsums[si], hcur, Wiou16, Wfh16, houpre, fpre, G1, G2);
        } else {
            G1 = 1; G2 = 1;
            gemm_level<64, 64, 256><<<dim3(G1 * 24 + G2 * 8), dim3(256), 0, stream>>>(
                hsums[si], hcur, Wiou16, Wfh16, houpre, fpre, G1, G2);
        }

        int npairs = (n > 1) ? (n >> 1) : 1;
        int blocks = (npairs * 128 + 255) / 256;
        float* fin = (lvl == 0) ? (float*)d_out : nullptr;
        combine_level<<<dim3(blocks), dim3(256), 0, stream>>>(
            houpre, fpre, cprev, Xp, cbufs[ci], hnext, hsums[si ^ 1], n, n - 1, fin);

        cprev = cbufs[ci];
        ci ^= 1; si ^= 1;
        _Float16* tmp = hcur; hcur = hnext; hnext = tmp;
    }
}